// Round 1
// baseline (3244.955 us; speedup 1.0000x reference)
//
#include <hip/hip_runtime.h>

typedef unsigned short u16;
typedef __attribute__((ext_vector_type(8))) short bf16x8;   // 8 bf16 = 4 VGPRs
typedef __attribute__((ext_vector_type(4))) float f32x4;

// ---- constants ----
// x: [8][512][64][64] f32 ; w: [1][256][512][3][3] f32 ; z: [8][256][128][128] f32
// ws layout: xp bf16 [8][66][66][512] (halo-padded NHWC) = 35,684,352 B at 0
//            H  bf16 [36][256][512]                       =  9,437,184 B at 35,684,352
#define XP_BYTES 35684352

__device__ inline u16 f2bf(float f) {
  union { float f; unsigned u; } v; v.f = f;
  unsigned r = v.u + 0x7fffu + ((v.u >> 16) & 1u);
  return (u16)(r >> 16);
}

__device__ inline void gl_lds16(const u16* g, u16* l) {
  __builtin_amdgcn_global_load_lds(
      (const __attribute__((address_space(1))) unsigned int*)g,
      (__attribute__((address_space(3))) unsigned int*)l, 16, 0, 0);
}

// ---------------- x prep: f32 NCHW -> bf16 NHWC with 1-px zero halo ----------------
// grid 4096 = n(8) * h(64) * cchunk(8), block 256
__global__ void xprep(const float* __restrict__ x, u16* __restrict__ xp) {
  __shared__ float tile[64 * 65];          // [w][ci], pad 65 to break bank conflicts
  int bid = blockIdx.x;
  int cc = bid & 7, h = (bid >> 3) & 63, n = bid >> 9;
  int c0 = cc * 64;
  int t = threadIdx.x;
  const float* xb = x + ((size_t)(n * 512 + c0) * 64 + h) * 64;
  for (int r = 0; r < 16; ++r) {
    int flat = r * 256 + t;
    int ci = flat >> 6, w = flat & 63;     // lanes sweep w -> coalesced read
    tile[w * 65 + ci] = xb[(size_t)ci * 4096 + w];
  }
  __syncthreads();
  u16* xpb = xp + ((size_t)(n * 66 + h + 1) * 66 + 1) * 512 + c0;
  for (int r = 0; r < 8; ++r) {
    int flat = r * 256 + t;
    int pr = flat & 31;                    // ci pair
    int w = flat >> 5;
    int ci = pr * 2;
    float v0 = tile[w * 65 + ci], v1 = tile[w * 65 + ci + 1];
    unsigned pk = (unsigned)f2bf(v0) | ((unsigned)f2bf(v1) << 16);
    *(unsigned*)(xpb + (size_t)w * 512 + ci) = pk;   // 4 B/lane, contiguous in ci
  }
}

// ---------------- weight prep: modulate+demod, fold FIR, 36 planes [o][i] bf16 ----------------
// grid 256 (block per o), block 256
__global__ void wprep(const float* __restrict__ w, u16* __restrict__ Hm) {
  __shared__ float wl[4608];
  __shared__ float red[256];
  int o = blockIdx.x, t = threadIdx.x;
  const float* wo = w + (size_t)o * 4608;
  float s = 0.f;
  for (int j = t; j < 4608; j += 256) { float v = wo[j]; wl[j] = v; s += v * v; }
  red[t] = s;
  __syncthreads();
  for (int st = 128; st; st >>= 1) { if (t < st) red[t] += red[t + st]; __syncthreads(); }
  float demod = rsqrtf(red[0] * (1.0f / 4608.0f) + 1e-6f);   // rsqrt(sum((w*ws)^2)+eps)
  float scale = demod * 0.014731391274719739f;               // * w_scale = 4608^-0.5
  const float F1[4] = {1.f, 3.f, 3.f, 1.f};
  for (int i = t; i < 512; i += 256) {
    float wm[9];
    for (int k = 0; k < 9; ++k) wm[k] = wl[i * 9 + k] * scale;
    for (int rp = 0; rp < 2; ++rp)
      for (int rq = 0; rq < 2; ++rq)
        for (int u = 0; u < 3; ++u)
          for (int v = 0; v < 3; ++v) {
            int s_ = 2 - 2 * u + rp, t_ = 2 - 2 * v + rq;
            float g = 0.f;
            for (int dy = 0; dy < 3; ++dy) {
              int a = dy + 1 - s_;
              if (a < 0 || a > 3) continue;
              for (int dx = 0; dx < 3; ++dx) {
                int b = dx + 1 - t_;
                if (b < 0 || b > 3) continue;
                g += wm[dy * 3 + dx] * (F1[a] * F1[b]);
              }
            }
            g *= 0.0625f;                                    // /16 FIR normalization
            Hm[(size_t)((rp * 2 + rq) * 9 + u * 3 + v) * 131072 + (size_t)o * 512 + i] = f2bf(g);
          }
  }
}

// ---------------- main fused conv: 4-phase 3x3, K=512, MFMA bf16 ----------------
// grid 2048: bid = mtile(256) * 8 + rp(2)*4 + ntile(4); block 256 (4 waves)
// block tile: 128 m (= 1 image, 2 hp-rows x 64 wq) x 64 o x both rq phases
__global__ __launch_bounds__(256) void conv_main(const u16* __restrict__ xp,
                                                 const u16* __restrict__ Hm,
                                                 float* __restrict__ z) {
  __shared__ __align__(16) float smemf[8448];   // 33,792 B: staging 16 KB / epilogue 4*2112 f32
  u16* su = (u16*)smemf;                        // A: [0,4096) u16, B: [4096,8192) u16

  int bid = blockIdx.x;
  int sub = bid & 7;
  int rp = sub >> 2;
  int o0 = (sub & 3) * 64;
  int mtile = bid >> 3;
  int n_img = mtile >> 5;
  int hp0 = (mtile & 31) * 2;

  int t = threadIdx.x;
  int wave = t >> 6, lane = t & 63;
  int wm0 = (wave & 1) * 64;       // wave m-offset (one hp row of 64 wq)
  int wn0 = (wave >> 1) * 32;      // wave n-offset
  int la = lane & 15;
  int ks = (lane >> 4) * 8;        // frag k element offset

  int rsel = t >> 2;               // staging row 0..63
  int koff = (t & 3) * 8;          // staging k element offset

  f32x4 acc[2][4][2];
  for (int a = 0; a < 2; ++a)
    for (int b = 0; b < 4; ++b)
      for (int c = 0; c < 2; ++c)
        for (int r = 0; r < 4; ++r) acc[a][b][c][r] = 0.f;

#pragma unroll 1
  for (int tap = 0; tap < 9; ++tap) {
    int du = tap / 3, dv = tap - du * 3;
    // A base: xp[n][hp0+du + (row>>6)][ (row&63)+dv ][c]
    const u16* gA0 = xp + ((size_t)(n_img * 66 + hp0 + du) * 66 + dv) * 512;
    // B base: Hm[plane][o0+row][c], plane = rp*18 + rq*9 + tap
    const u16* gB0 = Hm + (size_t)(rp * 18 + tap) * 131072 + (size_t)(o0 + rsel) * 512 + koff;
    const u16* gAr0 = gA0 + (size_t)rsel * 512 + koff;        // rows 0..63  (hp0)
    const u16* gAr1 = gA0 + (size_t)(66 + rsel) * 512 + koff; // rows 64..127 (hp0+1)

#pragma unroll 1
    for (int kc = 0; kc < 16; ++kc) {
      int c0 = kc * 32;
      __syncthreads();
      // stage A: 128 rows x 32 bf16 (two 4 KB rounds), lds offset = linear tid*16 B
      gl_lds16(gAr0 + c0, su + wave * 512);
      gl_lds16(gAr1 + c0, su + 2048 + wave * 512);
      // stage B: per rq phase, 64 rows x 32 bf16
      gl_lds16(gB0 + c0,               su + 4096 + wave * 512);
      gl_lds16(gB0 + 9 * 131072 + c0,  su + 6144 + wave * 512);
      __syncthreads();

      bf16x8 af[4];
#pragma unroll
      for (int ti = 0; ti < 4; ++ti)
        af[ti] = *(const bf16x8*)(su + (wm0 + ti * 16 + la) * 32 + ks);
      bf16x8 bfr[2][2];
#pragma unroll
      for (int rq = 0; rq < 2; ++rq)
#pragma unroll
        for (int tj = 0; tj < 2; ++tj)
          bfr[rq][tj] = *(const bf16x8*)(su + 4096 + rq * 2048 + (wn0 + tj * 16 + la) * 32 + ks);
#pragma unroll
      for (int rq = 0; rq < 2; ++rq)
#pragma unroll
        for (int ti = 0; ti < 4; ++ti)
#pragma unroll
          for (int tj = 0; tj < 2; ++tj)
            acc[rq][ti][tj] = __builtin_amdgcn_mfma_f32_16x16x32_bf16(
                af[ti], bfr[rq][tj], acc[rq][ti][tj], 0, 0, 0);
    }
  }

  // ---- epilogue: interleave rq in LDS (row stride 132 breaks bank alignment), dense f32x4 stores
  __syncthreads();
  float* lws = smemf + wave * 2112;              // [16 o][132] f32 per wave
  int p = 2 * (hp0 + (wave & 1)) + rp;
#pragma unroll 1
  for (int tj = 0; tj < 2; ++tj) {
#pragma unroll
    for (int rq = 0; rq < 2; ++rq)
#pragma unroll
      for (int ti = 0; ti < 4; ++ti) {
        int wqb = ti * 16 + (lane >> 4) * 4;     // C/D: row=(lane>>4)*4+reg, col=lane&15
        f32x4 v = acc[rq][ti][tj];
#pragma unroll
        for (int r = 0; r < 4; ++r)
          lws[la * 132 + 2 * (wqb + r) + rq] = v[r];
      }
    __syncthreads();
    int obase = o0 + wn0 + tj * 16;
#pragma unroll
    for (int c = 0; c < 8; ++c) {
      int idx = c * 64 + lane;
      int ol = idx >> 5, q4 = (idx & 31) * 4;
      f32x4 vv = *(const f32x4*)(lws + ol * 132 + q4);
      *(f32x4*)(z + (((size_t)n_img * 256 + obase + ol) * 128 + p) * 128 + q4) = vv;
    }
    __syncthreads();
  }
}

extern "C" void kernel_launch(void* const* d_in, const int* in_sizes, int n_in,
                              void* d_out, int out_size, void* d_ws, size_t ws_size,
                              hipStream_t stream) {
  const float* x = (const float*)d_in[0];
  const float* w = (const float*)d_in[1];
  float* z = (float*)d_out;
  u16* xp = (u16*)d_ws;
  u16* Hm = (u16*)((char*)d_ws + XP_BYTES);

  hipMemsetAsync(xp, 0, XP_BYTES, stream);              // zero halo
  xprep<<<4096, 256, 0, stream>>>(x, xp);
  wprep<<<256, 256, 0, stream>>>(w, Hm);
  conv_main<<<2048, 256, 0, stream>>>(xp, Hm, z);
}

// Round 2
// 568.049 us; speedup vs baseline: 5.7125x; 5.7125x over previous
//
#include <hip/hip_runtime.h>

typedef unsigned short u16;
typedef __attribute__((ext_vector_type(8))) short bf16x8;   // 8 bf16 = 4 VGPRs
typedef __attribute__((ext_vector_type(4))) float f32x4;

// ---- constants ----
// x: [8][512][64][64] f32 ; w: [1][256][512][3][3] f32 ; z: [8][256][128][128] f32
// ws layout: xp bf16 [8][66][66][512] (halo-padded NHWC) = 35,684,352 B at 0
//            H  bf16 [36][256][512]                       =  9,437,184 B at 35,684,352
#define XP_BYTES 35684352

__device__ inline u16 f2bf(float f) {
  union { float f; unsigned u; } v; v.f = f;
  unsigned r = v.u + 0x7fffu + ((v.u >> 16) & 1u);
  return (u16)(r >> 16);
}

__device__ inline void gl_lds16(const u16* g, u16* l) {
  __builtin_amdgcn_global_load_lds(
      (const __attribute__((address_space(1))) unsigned int*)g,
      (__attribute__((address_space(3))) unsigned int*)l, 16, 0, 0);
}

// ---------------- x prep: f32 NCHW -> bf16 NHWC with 1-px zero halo ----------------
// grid 4096 = n(8) * h(64) * cchunk(8), block 256
__global__ void xprep(const float* __restrict__ x, u16* __restrict__ xp) {
  __shared__ float tile[64 * 65];          // [w][ci], pad 65 to break bank conflicts
  int bid = blockIdx.x;
  int cc = bid & 7, h = (bid >> 3) & 63, n = bid >> 9;
  int c0 = cc * 64;
  int t = threadIdx.x;
  const float* xb = x + ((size_t)(n * 512 + c0) * 64 + h) * 64;
  for (int r = 0; r < 16; ++r) {
    int flat = r * 256 + t;
    int ci = flat >> 6, w = flat & 63;     // lanes sweep w -> coalesced read
    tile[w * 65 + ci] = xb[(size_t)ci * 4096 + w];
  }
  __syncthreads();
  u16* xpb = xp + ((size_t)(n * 66 + h + 1) * 66 + 1) * 512 + c0;
  for (int r = 0; r < 8; ++r) {
    int flat = r * 256 + t;
    int pr = flat & 31;                    // ci pair
    int w = flat >> 5;
    int ci = pr * 2;
    float v0 = tile[w * 65 + ci], v1 = tile[w * 65 + ci + 1];
    unsigned pk = (unsigned)f2bf(v0) | ((unsigned)f2bf(v1) << 16);
    *(unsigned*)(xpb + (size_t)w * 512 + ci) = pk;   // 4 B/lane, contiguous in ci
  }
}

// ---------------- weight prep: modulate+demod, fold FIR, 36 planes [o][i] bf16 ----------------
// grid 256 (block per o), block 256
__global__ void wprep(const float* __restrict__ w, u16* __restrict__ Hm) {
  __shared__ float wl[4608];
  __shared__ float red[256];
  int o = blockIdx.x, t = threadIdx.x;
  const float* wo = w + (size_t)o * 4608;
  float s = 0.f;
  for (int j = t; j < 4608; j += 256) { float v = wo[j]; wl[j] = v; s += v * v; }
  red[t] = s;
  __syncthreads();
  for (int st = 128; st; st >>= 1) { if (t < st) red[t] += red[t + st]; __syncthreads(); }
  float demod = rsqrtf(red[0] * (1.0f / 4608.0f) + 1e-6f);   // rsqrt(sum((w*ws)^2)+eps)
  float scale = demod * 0.014731391274719739f;               // * w_scale = 4608^-0.5
  const float F1[4] = {1.f, 3.f, 3.f, 1.f};
  for (int i = t; i < 512; i += 256) {
    float wm[9];
    for (int k = 0; k < 9; ++k) wm[k] = wl[i * 9 + k] * scale;
    for (int rp = 0; rp < 2; ++rp)
      for (int rq = 0; rq < 2; ++rq)
        for (int u = 0; u < 3; ++u)
          for (int v = 0; v < 3; ++v) {
            int s_ = 2 - 2 * u + rp, t_ = 2 - 2 * v + rq;
            float g = 0.f;
            for (int dy = 0; dy < 3; ++dy) {
              int a = dy + 1 - s_;
              if (a < 0 || a > 3) continue;
              for (int dx = 0; dx < 3; ++dx) {
                int b = dx + 1 - t_;
                if (b < 0 || b > 3) continue;
                g += wm[dy * 3 + dx] * (F1[a] * F1[b]);
              }
            }
            g *= 0.0625f;                                    // /16 FIR normalization
            Hm[(size_t)((rp * 2 + rq) * 9 + u * 3 + v) * 131072 + (size_t)o * 512 + i] = f2bf(g);
          }
  }
}

// ---------------- main fused conv: 4-phase 3x3, K=512, MFMA bf16 ----------------
// grid 2048: bid = mtile(256) * 8 + rp(2)*4 + ntile(4); block 256 (4 waves)
// block tile: 128 m (= 1 image, 2 hp-rows x 64 wq) x 64 o x both rq phases
__global__ __launch_bounds__(256) void conv_main(const u16* __restrict__ xp,
                                                 const u16* __restrict__ Hm,
                                                 float* __restrict__ z) {
  __shared__ __align__(16) float smemf[8448];   // 33,792 B: staging 16 KB / epilogue 4*2112 f32
  u16* su = (u16*)smemf;                        // A: [0,4096) u16, B: [4096,8192) u16

  int bid = blockIdx.x;
  int sub = bid & 7;
  int rp = sub >> 2;
  int o0 = (sub & 3) * 64;
  int mtile = bid >> 3;
  int n_img = mtile >> 5;
  int hp0 = (mtile & 31) * 2;

  int t = threadIdx.x;
  int wave = t >> 6, lane = t & 63;
  int wm0 = (wave & 1) * 64;       // wave m-offset (one hp row of 64 wq)
  int wn0 = (wave >> 1) * 32;      // wave n-offset
  int la = lane & 15;
  int ks = (lane >> 4) * 8;        // frag k element offset

  int rsel = t >> 2;               // staging row 0..63
  int koff = (t & 3) * 8;          // staging k element offset

  // all acc indices must be compile-time -> SROA into VGPRs/AGPRs (R1 spill fix)
  f32x4 acc[2][4][2];
#pragma unroll
  for (int a = 0; a < 2; ++a)
#pragma unroll
    for (int b = 0; b < 4; ++b)
#pragma unroll
      for (int c = 0; c < 2; ++c)
        acc[a][b][c] = (f32x4){0.f, 0.f, 0.f, 0.f};

#pragma unroll 1
  for (int tap = 0; tap < 9; ++tap) {
    int du = tap / 3, dv = tap - du * 3;
    // A base: xp[n][hp0+du + (row>>6)][ (row&63)+dv ][c]
    const u16* gA0 = xp + ((size_t)(n_img * 66 + hp0 + du) * 66 + dv) * 512;
    // B base: Hm[plane][o0+row][c], plane = rp*18 + rq*9 + tap
    const u16* gB0 = Hm + (size_t)(rp * 18 + tap) * 131072 + (size_t)(o0 + rsel) * 512 + koff;
    const u16* gAr0 = gA0 + (size_t)rsel * 512 + koff;        // rows 0..63  (hp0)
    const u16* gAr1 = gA0 + (size_t)(66 + rsel) * 512 + koff; // rows 64..127 (hp0+1)

#pragma unroll 1
    for (int kc = 0; kc < 16; ++kc) {
      int c0 = kc * 32;
      __syncthreads();
      // stage A: 128 rows x 32 bf16 (two 4 KB rounds), lds offset = linear tid*16 B
      gl_lds16(gAr0 + c0, su + wave * 512);
      gl_lds16(gAr1 + c0, su + 2048 + wave * 512);
      // stage B: per rq phase, 64 rows x 32 bf16
      gl_lds16(gB0 + c0,               su + 4096 + wave * 512);
      gl_lds16(gB0 + 9 * 131072 + c0,  su + 6144 + wave * 512);
      __syncthreads();

      bf16x8 af[4];
#pragma unroll
      for (int ti = 0; ti < 4; ++ti)
        af[ti] = *(const bf16x8*)(su + (wm0 + ti * 16 + la) * 32 + ks);
      bf16x8 bfr[2][2];
#pragma unroll
      for (int rq = 0; rq < 2; ++rq)
#pragma unroll
        for (int tj = 0; tj < 2; ++tj)
          bfr[rq][tj] = *(const bf16x8*)(su + 4096 + rq * 2048 + (wn0 + tj * 16 + la) * 32 + ks);
#pragma unroll
      for (int rq = 0; rq < 2; ++rq)
#pragma unroll
        for (int ti = 0; ti < 4; ++ti)
#pragma unroll
          for (int tj = 0; tj < 2; ++tj)
            acc[rq][ti][tj] = __builtin_amdgcn_mfma_f32_16x16x32_bf16(
                af[ti], bfr[rq][tj], acc[rq][ti][tj], 0, 0, 0);
    }
  }

  // ---- epilogue: interleave rq in LDS (row stride 132 breaks bank alignment), dense f32x4 stores
  // FULLY UNROLLED (tj compile-time) so acc stays in registers — R1's 8x spill bug.
  __syncthreads();
  float* lws = smemf + wave * 2112;              // [16 o][132] f32 per wave
  int p = 2 * (hp0 + (wave & 1)) + rp;
#pragma unroll
  for (int tj = 0; tj < 2; ++tj) {
#pragma unroll
    for (int rq = 0; rq < 2; ++rq)
#pragma unroll
      for (int ti = 0; ti < 4; ++ti) {
        int wqb = ti * 16 + (lane >> 4) * 4;     // C/D: row=(lane>>4)*4+reg, col=lane&15
        f32x4 v = acc[rq][ti][tj];
#pragma unroll
        for (int r = 0; r < 4; ++r)
          lws[la * 132 + 2 * (wqb + r) + rq] = v[r];
      }
    __syncthreads();
    int obase = o0 + wn0 + tj * 16;
#pragma unroll
    for (int c = 0; c < 8; ++c) {
      int idx = c * 64 + lane;
      int ol = idx >> 5, q4 = (idx & 31) * 4;
      f32x4 vv = *(const f32x4*)(lws + ol * 132 + q4);
      *(f32x4*)(z + (((size_t)n_img * 256 + obase + ol) * 128 + p) * 128 + q4) = vv;
    }
    __syncthreads();
  }
}

extern "C" void kernel_launch(void* const* d_in, const int* in_sizes, int n_in,
                              void* d_out, int out_size, void* d_ws, size_t ws_size,
                              hipStream_t stream) {
  const float* x = (const float*)d_in[0];
  const float* w = (const float*)d_in[1];
  float* z = (float*)d_out;
  u16* xp = (u16*)d_ws;
  u16* Hm = (u16*)((char*)d_ws + XP_BYTES);

  hipMemsetAsync(xp, 0, XP_BYTES, stream);              // zero halo
  xprep<<<4096, 256, 0, stream>>>(x, xp);
  wprep<<<256, 256, 0, stream>>>(w, Hm);
  conv_main<<<2048, 256, 0, stream>>>(xp, Hm, z);
}

// Round 3
// 402.497 us; speedup vs baseline: 8.0621x; 1.4113x over previous
//
#include <hip/hip_runtime.h>

typedef unsigned short u16;
typedef unsigned int u32;
typedef __attribute__((ext_vector_type(8))) short bf16x8;   // 8 bf16 = 4 VGPRs
typedef __attribute__((ext_vector_type(4))) float f32x4;

// ---- ws layout (new path) ----
// xp bf16 [8][66][66][512] halo-padded NHWC : 35,684,352 B at 0
// yb bf16 [8][256][131][132] halo-padded y  : 70,828,032 B at XP_BYTES
// Hy bf16 [9][256][512]                     :  2,359,296 B at HY_OFF
#define XP_BYTES 35684352
#define YB_BYTES 70828032
#define HY_OFF   (XP_BYTES + YB_BYTES)
#define HY_BYTES 2359296
#define WS_NEED  ((size_t)HY_OFF + HY_BYTES)   // 108,871,680

__device__ inline u16 f2bf(float f) {
  union { float f; unsigned u; } v; v.f = f;
  unsigned r = v.u + 0x7fffu + ((v.u >> 16) & 1u);
  return (u16)(r >> 16);
}

__device__ inline void gl_lds16(const u16* g, u16* l) {
  __builtin_amdgcn_global_load_lds(
      (const __attribute__((address_space(1))) unsigned int*)g,
      (__attribute__((address_space(3))) unsigned int*)l, 16, 0, 0);
}

// ---------------- x prep: f32 NCHW -> bf16 NHWC with 1-px zero halo (self-zeroing halos) ----
// grid 4096 = n(8) * h(64) * cchunk(8), block 256
__global__ void xprep(const float* __restrict__ x, u16* __restrict__ xp) {
  __shared__ float tile[64 * 65];
  int bid = blockIdx.x;
  int cc = bid & 7, h = (bid >> 3) & 63, n = bid >> 9;
  int c0 = cc * 64;
  int t = threadIdx.x;
  const float* xb = x + ((size_t)(n * 512 + c0) * 64 + h) * 64;
  for (int r = 0; r < 16; ++r) {
    int flat = r * 256 + t;
    int ci = flat >> 6, w = flat & 63;
    tile[w * 65 + ci] = xb[(size_t)ci * 4096 + w];
  }
  __syncthreads();
  u16* xpb = xp + ((size_t)(n * 66 + h + 1) * 66 + 1) * 512 + c0;
  for (int r = 0; r < 8; ++r) {
    int flat = r * 256 + t;
    int pr = flat & 31;
    int w = flat >> 5;
    int ci = pr * 2;
    float v0 = tile[w * 65 + ci], v1 = tile[w * 65 + ci + 1];
    unsigned pk = (unsigned)f2bf(v0) | ((unsigned)f2bf(v1) << 16);
    *(unsigned*)(xpb + (size_t)w * 512 + ci) = pk;
  }
  // col halos (cols 0 and 65) of this row, this channel chunk
  u16* rowbase = xp + ((size_t)(n * 66 + h + 1) * 66) * 512 + c0;
  if (t < 32) *(u32*)(rowbase + 2 * t) = 0u;
  else if (t < 64) *(u32*)(rowbase + (size_t)65 * 512 + 2 * (t - 32)) = 0u;
  // row halos (rows 0 and 65)
  if (h == 0) {
    u16* r0 = xp + ((size_t)(n * 66) * 66) * 512 + c0;
    for (int j = t; j < 2112; j += 256) {
      int col = j >> 5, wi = j & 31;
      *(u32*)(r0 + (size_t)col * 512 + 2 * wi) = 0u;
    }
  }
  if (h == 63) {
    u16* r65 = xp + ((size_t)(n * 66 + 65) * 66) * 512 + c0;
    for (int j = t; j < 2112; j += 256) {
      int col = j >> 5, wi = j & 31;
      *(u32*)(r65 + (size_t)col * 512 + 2 * wi) = 0u;
    }
  }
}

// ---------------- weight prep (new): modulate+demod, 9 conv-transpose tap planes ----------------
// plane -> wm[dy][dx]:  ph(0,0): (0,0),(2,0),(0,2),(2,2) | ph(0,1): (0,1),(2,1)
//                       ph(1,0): (1,0),(1,2)             | ph(1,1): (1,1)
__global__ void wprep9(const float* __restrict__ w, u16* __restrict__ Hy) {
  __shared__ float wl[4608];
  __shared__ float red[256];
  int o = blockIdx.x, t = threadIdx.x;
  const float* wo = w + (size_t)o * 4608;
  float s = 0.f;
  for (int j = t; j < 4608; j += 256) { float v = wo[j]; wl[j] = v; s += v * v; }
  red[t] = s;
  __syncthreads();
  for (int st = 128; st; st >>= 1) { if (t < st) red[t] += red[t + st]; __syncthreads(); }
  float demod = rsqrtf(red[0] * (1.0f / 4608.0f) + 1e-6f);
  float scale = demod * 0.014731391274719739f;   // * (FI*K*K)^-0.5
  const int DY[9] = {0, 2, 0, 2, 0, 2, 1, 1, 1};
  const int DX[9] = {0, 0, 2, 2, 1, 1, 0, 2, 1};
  for (int i = t; i < 512; i += 256) {
#pragma unroll
    for (int pl = 0; pl < 9; ++pl) {
      float g = wl[i * 9 + DY[pl] * 3 + DX[pl]] * scale;
      Hy[(size_t)pl * 131072 + (size_t)o * 512 + i] = f2bf(g);
    }
  }
}

// ---------------- pass 1: conv-transpose y, 4 parity phases, MFMA bf16 ----------------
// y[2a+rp][2b+rq][o] = sum_i sum_taps x[a-du][b-dv][i] * wm[...] ; flattened m = a*W + b
// grid 2112 = ph0:544 | ph1:528 | ph2:528 | ph3:512 (heavy K first), block 256 (4 waves)
// block tile 128m x 128n, BK=64, XOR-swizzled LDS chunks (swizzle applied in gather addrs)
__global__ __launch_bounds__(256) void conv_y(const u16* __restrict__ xp,
                                              const u16* __restrict__ Hy,
                                              u16* __restrict__ yb) {
  __shared__ __align__(16) u16 su[16384];   // A [0,8192) B [8192,16384) u16 = 32 KB

  int bid = blockIdx.x;
  int t = threadIdx.x;
  int wave = t >> 6, lane = t & 63;

  int mt, nt, img, W, CNT, NTAP, PB, rp, rq;
  if (bid < 544)       { int s2 = bid;        mt = s2 % 34; int r2 = s2 / 34; nt = r2 & 1; img = r2 >> 1; W = 65; CNT = 4225; NTAP = 4; PB = 0; rp = 0; rq = 0; }
  else if (bid < 1072) { int s2 = bid - 544;  mt = s2 % 33; int r2 = s2 / 33; nt = r2 & 1; img = r2 >> 1; W = 64; CNT = 4160; NTAP = 2; PB = 4; rp = 0; rq = 1; }
  else if (bid < 1600) { int s2 = bid - 1072; mt = s2 % 33; int r2 = s2 / 33; nt = r2 & 1; img = r2 >> 1; W = 65; CNT = 4160; NTAP = 2; PB = 6; rp = 1; rq = 0; }
  else                 { int s2 = bid - 1600; mt = s2 % 32; int r2 = s2 / 32; nt = r2 & 1; img = r2 >> 1; W = 64; CNT = 4096; NTAP = 1; PB = 8; rp = 1; rq = 1; }

  int m0 = mt * 128;
  int o0 = nt * 128;
  int wm0 = (wave & 1) * 64;
  int wn0 = (wave >> 1) * 64;
  int la = lane & 15, grp = lane >> 4;

  int rho = t >> 3;                       // staging row 0..31 (per issue +32*i)
  int gch = (t & 7) ^ (rho & 7);          // fetch chunk so LDS slot g holds chunk g^(row&7)

  u32 gA[4];
#pragma unroll
  for (int i = 0; i < 4; ++i) {
    int m = m0 + rho + i * 32;
    if (m > CNT - 1) m = CNT - 1;         // clamp (garbage compute, epilogue skips)
    int a = (W == 65) ? (m / 65) : (m >> 6);
    int b = m - a * W;
    gA[i] = (u32)(((img * 66 + a + 1) * 66 + (b + 1)) * 512 + gch * 8);
  }
  u32 gB[4];
#pragma unroll
  for (int i = 0; i < 4; ++i)
    gB[i] = (u32)((o0 + i * 32 + rho) * 512 + gch * 8);

  f32x4 acc[4][4];
#pragma unroll
  for (int i = 0; i < 4; ++i)
#pragma unroll
    for (int j = 0; j < 4; ++j) acc[i][j] = (f32x4){0.f, 0.f, 0.f, 0.f};

  for (int tap = 0; tap < NTAP; ++tap) {
    int du, dv;
    if (rp == 0 && rq == 0)      { du = tap & 1; dv = tap >> 1; }
    else if (rp == 0)            { du = tap;     dv = 0; }
    else if (rq == 0)            { du = 0;       dv = tap; }
    else                         { du = 0;       dv = 0; }
    u32 tapadj = (u32)((du * 66 + dv) * 512);
    const u16* hp = Hy + (size_t)(PB + tap) * 131072;

#pragma unroll 1
    for (int kc = 0; kc < 8; ++kc) {
      u32 ko = (u32)(kc * 64);
      __syncthreads();
#pragma unroll
      for (int i = 0; i < 4; ++i)
        gl_lds16(xp + (gA[i] - tapadj + ko), su + i * 2048 + wave * 512);
#pragma unroll
      for (int i = 0; i < 4; ++i)
        gl_lds16(hp + (gB[i] + ko), su + 8192 + i * 2048 + wave * 512);
      __syncthreads();

#pragma unroll
      for (int ksub = 0; ksub < 2; ++ksub) {
        bf16x8 af[4], bf[4];
#pragma unroll
        for (int ti = 0; ti < 4; ++ti) {
          int row = wm0 + ti * 16 + la;
          int ch = (ksub * 4 + grp) ^ (row & 7);
          af[ti] = *(const bf16x8*)(su + row * 64 + ch * 8);
        }
#pragma unroll
        for (int tj = 0; tj < 4; ++tj) {
          int row = wn0 + tj * 16 + la;
          int ch = (ksub * 4 + grp) ^ (row & 7);
          bf[tj] = *(const bf16x8*)(su + 8192 + row * 64 + ch * 8);
        }
#pragma unroll
        for (int ti = 0; ti < 4; ++ti)
#pragma unroll
          for (int tj = 0; tj < 4; ++tj)
            acc[ti][tj] = __builtin_amdgcn_mfma_f32_16x16x32_bf16(
                af[ti], bf[tj], acc[ti][tj], 0, 0, 0);
      }
    }
  }

  // ---- epilogue: acc -> LDS [64 o][136 m] bf16 (two o-halves), strided u16 stores into yb
  // (stride-2 spatial interleave of phases makes contiguous vector stores impossible; L2 merges)
#pragma unroll
  for (int h = 0; h < 2; ++h) {
    __syncthreads();
    if ((wave >> 1) == h) {
#pragma unroll
      for (int tj = 0; tj < 4; ++tj) {
        int ol = tj * 16 + la;
#pragma unroll
        for (int ti = 0; ti < 4; ++ti)
#pragma unroll
          for (int jp = 0; jp < 2; ++jp) {
            int ml = wm0 + ti * 16 + grp * 4 + jp * 2;
            u32 pk = (u32)f2bf(acc[ti][tj][jp * 2]) |
                     ((u32)f2bf(acc[ti][tj][jp * 2 + 1]) << 16);
            *(u32*)(su + ol * 136 + ml) = pk;
          }
      }
    }
    __syncthreads();
#pragma unroll
    for (int iter = 0; iter < 4; ++iter) {
      int flat = iter * 256 + t;
      int ol = flat >> 4, s8 = flat & 15;
      int ml = s8 * 8;
      int m = m0 + ml;
      if (m < CNT) {
        int a = (W == 65) ? (m / 65) : (m >> 6);
        int b = m - a * W;
        bf16x8 v = *(const bf16x8*)(su + ol * 136 + ml);
        int og = o0 + h * 64 + ol;
        size_t pb = (size_t)(img * 256 + og) * (131 * 132);
        int ae = a, be = b;
#pragma unroll
        for (int e = 0; e < 8; ++e) {
          if (m + e < CNT) {
            int r_ = 2 * ae + rp + 1;
            int c_ = 2 * be + rq + 1;
            yb[pb + (size_t)r_ * 132 + c_] = (u16)v[e];
          }
          ++be;
          if (be == W) { be = 0; ++ae; }
        }
      }
    }
    __syncthreads();
  }
}

// ---------------- pass 2: depthwise 4x4 FIR (separable 1,3,3,1), memory-bound ----------------
// thread: 4p x 4q block of z for one (n,o); reads yb rows 4p'..4p'+6, cols 4q'..4q'+7
__global__ void fir(const u16* __restrict__ yb, float* __restrict__ z) {
  int flat = blockIdx.x * 256 + threadIdx.x;
  int qh = flat & 31, ph_ = (flat >> 5) & 31, o = (flat >> 10) & 255, n = flat >> 18;
  const u16* base = yb + ((size_t)(n * 256 + o) * 131 + ph_ * 4) * 132 + qh * 4;
  float hrow[7][4];
#pragma unroll
  for (int r = 0; r < 7; ++r) {
    uint2 l0 = *(const uint2*)(base + (size_t)r * 132);
    uint2 l1 = *(const uint2*)(base + (size_t)r * 132 + 4);
    u32 wsv[4] = {l0.x, l0.y, l1.x, l1.y};
    float v[8];
#pragma unroll
    for (int j = 0; j < 4; ++j) {
      v[2 * j]     = __uint_as_float(wsv[j] << 16);
      v[2 * j + 1] = __uint_as_float(wsv[j] & 0xffff0000u);
    }
#pragma unroll
    for (int j = 0; j < 4; ++j)
      hrow[r][j] = v[j] + 3.f * (v[j + 1] + v[j + 2]) + v[j + 3];
  }
  float* zb = z + ((size_t)(n * 256 + o) * 128 + ph_ * 4) * 128 + qh * 4;
#pragma unroll
  for (int k = 0; k < 4; ++k) {
    f32x4 out;
#pragma unroll
    for (int j = 0; j < 4; ++j)
      out[j] = (hrow[k][j] + 3.f * (hrow[k + 1][j] + hrow[k + 2][j]) + hrow[k + 3][j]) * 0.0625f;
    *(f32x4*)(zb + (size_t)k * 128) = out;
  }
}

// ================= R2 fallback path (proven): FIR-folded fused conv =================
__global__ void wprep36(const float* __restrict__ w, u16* __restrict__ Hm) {
  __shared__ float wl[4608];
  __shared__ float red[256];
  int o = blockIdx.x, t = threadIdx.x;
  const float* wo = w + (size_t)o * 4608;
  float s = 0.f;
  for (int j = t; j < 4608; j += 256) { float v = wo[j]; wl[j] = v; s += v * v; }
  red[t] = s;
  __syncthreads();
  for (int st = 128; st; st >>= 1) { if (t < st) red[t] += red[t + st]; __syncthreads(); }
  float demod = rsqrtf(red[0] * (1.0f / 4608.0f) + 1e-6f);
  float scale = demod * 0.014731391274719739f;
  const float F1[4] = {1.f, 3.f, 3.f, 1.f};
  for (int i = t; i < 512; i += 256) {
    float wm[9];
    for (int k = 0; k < 9; ++k) wm[k] = wl[i * 9 + k] * scale;
    for (int rp = 0; rp < 2; ++rp)
      for (int rq = 0; rq < 2; ++rq)
        for (int u = 0; u < 3; ++u)
          for (int v = 0; v < 3; ++v) {
            int s_ = 2 - 2 * u + rp, t_ = 2 - 2 * v + rq;
            float g = 0.f;
            for (int dy = 0; dy < 3; ++dy) {
              int a = dy + 1 - s_;
              if (a < 0 || a > 3) continue;
              for (int dx = 0; dx < 3; ++dx) {
                int b = dx + 1 - t_;
                if (b < 0 || b > 3) continue;
                g += wm[dy * 3 + dx] * (F1[a] * F1[b]);
              }
            }
            g *= 0.0625f;
            Hm[(size_t)((rp * 2 + rq) * 9 + u * 3 + v) * 131072 + (size_t)o * 512 + i] = f2bf(g);
          }
  }
}

__global__ __launch_bounds__(256) void conv_main(const u16* __restrict__ xp,
                                                 const u16* __restrict__ Hm,
                                                 float* __restrict__ z) {
  __shared__ __align__(16) float smemf[8448];
  u16* su = (u16*)smemf;
  int bid = blockIdx.x;
  int sub = bid & 7;
  int rp = sub >> 2;
  int o0 = (sub & 3) * 64;
  int mtile = bid >> 3;
  int n_img = mtile >> 5;
  int hp0 = (mtile & 31) * 2;
  int t = threadIdx.x;
  int wave = t >> 6, lane = t & 63;
  int wm0 = (wave & 1) * 64;
  int wn0 = (wave >> 1) * 32;
  int la = lane & 15;
  int ks = (lane >> 4) * 8;
  int rsel = t >> 2;
  int koff = (t & 3) * 8;
  f32x4 acc[2][4][2];
#pragma unroll
  for (int a = 0; a < 2; ++a)
#pragma unroll
    for (int b = 0; b < 4; ++b)
#pragma unroll
      for (int c = 0; c < 2; ++c)
        acc[a][b][c] = (f32x4){0.f, 0.f, 0.f, 0.f};
#pragma unroll 1
  for (int tap = 0; tap < 9; ++tap) {
    int du = tap / 3, dv = tap - du * 3;
    const u16* gA0 = xp + ((size_t)(n_img * 66 + hp0 + du) * 66 + dv) * 512;
    const u16* gB0 = Hm + (size_t)(rp * 18 + tap) * 131072 + (size_t)(o0 + rsel) * 512 + koff;
    const u16* gAr0 = gA0 + (size_t)rsel * 512 + koff;
    const u16* gAr1 = gA0 + (size_t)(66 + rsel) * 512 + koff;
#pragma unroll 1
    for (int kc = 0; kc < 16; ++kc) {
      int c0 = kc * 32;
      __syncthreads();
      gl_lds16(gAr0 + c0, su + wave * 512);
      gl_lds16(gAr1 + c0, su + 2048 + wave * 512);
      gl_lds16(gB0 + c0,              su + 4096 + wave * 512);
      gl_lds16(gB0 + 9 * 131072 + c0, su + 6144 + wave * 512);
      __syncthreads();
      bf16x8 af[4];
#pragma unroll
      for (int ti = 0; ti < 4; ++ti)
        af[ti] = *(const bf16x8*)(su + (wm0 + ti * 16 + la) * 32 + ks);
      bf16x8 bfr[2][2];
#pragma unroll
      for (int rqq = 0; rqq < 2; ++rqq)
#pragma unroll
        for (int tj = 0; tj < 2; ++tj)
          bfr[rqq][tj] = *(const bf16x8*)(su + 4096 + rqq * 2048 + (wn0 + tj * 16 + la) * 32 + ks);
#pragma unroll
      for (int rqq = 0; rqq < 2; ++rqq)
#pragma unroll
        for (int ti = 0; ti < 4; ++ti)
#pragma unroll
          for (int tj = 0; tj < 2; ++tj)
            acc[rqq][ti][tj] = __builtin_amdgcn_mfma_f32_16x16x32_bf16(
                af[ti], bfr[rqq][tj], acc[rqq][ti][tj], 0, 0, 0);
    }
  }
  __syncthreads();
  float* lws = smemf + wave * 2112;
  int p = 2 * (hp0 + (wave & 1)) + rp;
#pragma unroll
  for (int tj = 0; tj < 2; ++tj) {
#pragma unroll
    for (int rqq = 0; rqq < 2; ++rqq)
#pragma unroll
      for (int ti = 0; ti < 4; ++ti) {
        int wqb = ti * 16 + (lane >> 4) * 4;
        f32x4 v = acc[rqq][ti][tj];
#pragma unroll
        for (int r = 0; r < 4; ++r)
          lws[la * 132 + 2 * (wqb + r) + rqq] = v[r];
      }
    __syncthreads();
    int obase = o0 + wn0 + tj * 16;
#pragma unroll
    for (int c = 0; c < 8; ++c) {
      int idx = c * 64 + lane;
      int ol = idx >> 5, q4 = (idx & 31) * 4;
      f32x4 vv = *(const f32x4*)(lws + ol * 132 + q4);
      *(f32x4*)(z + (((size_t)n_img * 256 + obase + ol) * 128 + p) * 128 + q4) = vv;
    }
    __syncthreads();
  }
}

extern "C" void kernel_launch(void* const* d_in, const int* in_sizes, int n_in,
                              void* d_out, int out_size, void* d_ws, size_t ws_size,
                              hipStream_t stream) {
  const float* x = (const float*)d_in[0];
  const float* w = (const float*)d_in[1];
  float* z = (float*)d_out;
  u16* xp = (u16*)d_ws;

  if (ws_size >= WS_NEED) {
    u16* yb = (u16*)((char*)d_ws + XP_BYTES);
    u16* hy = (u16*)((char*)d_ws + HY_OFF);
    hipMemsetAsync(yb, 0, YB_BYTES, stream);      // zero y halos (+interior, overwritten)
    xprep<<<4096, 256, 0, stream>>>(x, xp);       // self-zeroing xp halos
    wprep9<<<256, 256, 0, stream>>>(w, hy);
    conv_y<<<2112, 256, 0, stream>>>(xp, hy, yb);
    fir<<<8192, 256, 0, stream>>>(yb, z);
  } else {
    // fallback: proven R2 fused path (needs only 45.1 MB ws)
    u16* Hm = (u16*)((char*)d_ws + XP_BYTES);
    hipMemsetAsync(xp, 0, XP_BYTES, stream);
    xprep<<<4096, 256, 0, stream>>>(x, xp);
    wprep36<<<256, 256, 0, stream>>>(w, Hm);
    conv_main<<<2048, 256, 0, stream>>>(xp, Hm, z);
  }
}

// Round 5
// 333.796 us; speedup vs baseline: 9.7214x; 1.2058x over previous
//
#include <hip/hip_runtime.h>

typedef unsigned short u16;
typedef unsigned int u32;
typedef __attribute__((ext_vector_type(8))) short bf16x8;   // 8 bf16 = 4 VGPRs
typedef __attribute__((ext_vector_type(4))) float f32x4;

// ---- ws layout (planar path) ----
// xp bf16 [8][66][66][512] halo-padded NHWC : 35,684,352 B at 0
// yb: 8 u16 lead pad + 2048 chunks x 16776 u16 + 16 u16 trail = 68,714,544 B
//   per (img,o) chunk: plane0 (65x66) @0 sz4296 | plane1 (65x64) @4296 sz4160
//                      plane2 (64x66) @8456 sz4224 | plane3 (64x64) @12680 sz4096
// Hy bf16 [9][256][512] = 2,359,296 B
#define XP_BYTES 35684352
#define YB_BYTES 68714544
#define HY_OFF   (XP_BYTES + YB_BYTES)          // 104,398,896
#define WS_NEED  ((size_t)HY_OFF + 2359296)     // 106,758,192
#define CS 16776                                 // chunk stride (u16)

__device__ inline u16 f2bf(float f) {
  union { float f; unsigned u; } v; v.f = f;
  unsigned r = v.u + 0x7fffu + ((v.u >> 16) & 1u);
  return (u16)(r >> 16);
}

__device__ inline void gl_lds16(const u16* g, u16* l) {
  __builtin_amdgcn_global_load_lds(
      (const __attribute__((address_space(1))) unsigned int*)g,
      (__attribute__((address_space(3))) unsigned int*)l, 16, 0, 0);
}

// ---------------- x prep: f32 NCHW -> bf16 NHWC with 1-px zero halo (self-zeroing) ----------
__global__ void xprep(const float* __restrict__ x, u16* __restrict__ xp) {
  __shared__ float tile[64 * 65];
  int bid = blockIdx.x;
  int cc = bid & 7, h = (bid >> 3) & 63, n = bid >> 9;
  int c0 = cc * 64;
  int t = threadIdx.x;
  const float* xb = x + ((size_t)(n * 512 + c0) * 64 + h) * 64;
  for (int r = 0; r < 16; ++r) {
    int flat = r * 256 + t;
    int ci = flat >> 6, w = flat & 63;
    tile[w * 65 + ci] = xb[(size_t)ci * 4096 + w];
  }
  __syncthreads();
  u16* xpb = xp + ((size_t)(n * 66 + h + 1) * 66 + 1) * 512 + c0;
  for (int r = 0; r < 8; ++r) {
    int flat = r * 256 + t;
    int pr = flat & 31;
    int w = flat >> 5;
    int ci = pr * 2;
    float v0 = tile[w * 65 + ci], v1 = tile[w * 65 + ci + 1];
    unsigned pk = (unsigned)f2bf(v0) | ((unsigned)f2bf(v1) << 16);
    *(unsigned*)(xpb + (size_t)w * 512 + ci) = pk;
  }
  u16* rowbase = xp + ((size_t)(n * 66 + h + 1) * 66) * 512 + c0;
  if (t < 32) *(u32*)(rowbase + 2 * t) = 0u;
  else if (t < 64) *(u32*)(rowbase + (size_t)65 * 512 + 2 * (t - 32)) = 0u;
  if (h == 0) {
    u16* r0 = xp + ((size_t)(n * 66) * 66) * 512 + c0;
    for (int j = t; j < 2112; j += 256) {
      int col = j >> 5, wi = j & 31;
      *(u32*)(r0 + (size_t)col * 512 + 2 * wi) = 0u;
    }
  }
  if (h == 63) {
    u16* r65 = xp + ((size_t)(n * 66 + 65) * 66) * 512 + c0;
    for (int j = t; j < 2112; j += 256) {
      int col = j >> 5, wi = j & 31;
      *(u32*)(r65 + (size_t)col * 512 + 2 * wi) = 0u;
    }
  }
}

// ---------------- weight prep: modulate+demod, 9 conv-transpose tap planes ----------------
__global__ void wprep9(const float* __restrict__ w, u16* __restrict__ Hy) {
  __shared__ float wl[4608];
  __shared__ float red[256];
  int o = blockIdx.x, t = threadIdx.x;
  const float* wo = w + (size_t)o * 4608;
  float s = 0.f;
  for (int j = t; j < 4608; j += 256) { float v = wo[j]; wl[j] = v; s += v * v; }
  red[t] = s;
  __syncthreads();
  for (int st = 128; st; st >>= 1) { if (t < st) red[t] += red[t + st]; __syncthreads(); }
  float demod = rsqrtf(red[0] * (1.0f / 4608.0f) + 1e-6f);
  float scale = demod * 0.014731391274719739f;
  const int DY[9] = {0, 2, 0, 2, 0, 2, 1, 1, 1};
  const int DX[9] = {0, 0, 2, 2, 1, 1, 0, 2, 1};
  for (int i = t; i < 512; i += 256) {
#pragma unroll
    for (int pl = 0; pl < 9; ++pl) {
      float g = wl[i * 9 + DY[pl] * 3 + DX[pl]] * scale;
      Hy[(size_t)pl * 131072 + (size_t)o * 512 + i] = f2bf(g);
    }
  }
}

// ---------------- pass 1: conv-transpose y into planar phase buffers ----------------
// grid 2112 heavy-first; block tile 128m x 128o; BK=64; XOR-swizzled LDS; dense epilogue
__global__ __launch_bounds__(256) void conv_y(const u16* __restrict__ xp,
                                              const u16* __restrict__ Hy,
                                              u16* __restrict__ yb) {
  __shared__ __align__(16) u16 su[17408];   // K-loop: A[0,8192) B[8192,16384); epi: [128][136]

  int bid = blockIdx.x;
  int t = threadIdx.x;
  int wave = t >> 6, lane = t & 63;

  int mt, nt, img, Wp, CNT, NTAP, PB, PO, STLIM, rp, rq;
  if (bid < 544)       { int L = bid;        mt = L % 34; int r2 = L / 34; nt = r2 & 1; img = r2 >> 1; Wp = 66; CNT = 4290; NTAP = 4; PB = 0; PO = 0;     STLIM = 4296; rp = 0; rq = 0; }
  else if (bid < 1072) { int L = bid - 544;  mt = L % 33; int r2 = L / 33; nt = r2 & 1; img = r2 >> 1; Wp = 64; CNT = 4160; NTAP = 2; PB = 4; PO = 4296;  STLIM = 4160; rp = 0; rq = 1; }
  else if (bid < 1600) { int L = bid - 1072; mt = L % 33; int r2 = L / 33; nt = r2 & 1; img = r2 >> 1; Wp = 66; CNT = 4224; NTAP = 2; PB = 6; PO = 8456;  STLIM = 4224; rp = 1; rq = 0; }
  else                 { int L = bid - 1600; mt = L % 32; int r2 = L / 32; nt = r2 & 1; img = r2 >> 1; Wp = 64; CNT = 4096; NTAP = 1; PB = 8; PO = 12680; STLIM = 4096; rp = 1; rq = 1; }

  int m0 = mt * 128;
  int o0 = nt * 128;
  int wm0 = (wave & 1) * 64;
  int wn0 = (wave >> 1) * 64;
  int la = lane & 15, grp = lane >> 4;

  int rho = t >> 3;                       // staging row 0..31 (+32*i per issue)
  int gch = (t & 7) ^ (rho & 7);          // XOR chunk swizzle in gather addresses

  u32 gA[4];
#pragma unroll
  for (int i = 0; i < 4; ++i) {
    int m = m0 + rho + i * 32;
    if (m > CNT - 1) m = CNT - 1;         // clamp (garbage compute, store-guarded)
    int a = m / (u32)Wp;
    int b = m - a * Wp;
    gA[i] = (u32)(((img * 66 + a + 1) * 66 + (b + 1)) * 512 + gch * 8);
  }
  u32 gB[4];
#pragma unroll
  for (int i = 0; i < 4; ++i)
    gB[i] = (u32)((o0 + i * 32 + rho) * 512 + gch * 8);

  f32x4 acc[4][4];
#pragma unroll
  for (int i = 0; i < 4; ++i)
#pragma unroll
    for (int j = 0; j < 4; ++j) acc[i][j] = (f32x4){0.f, 0.f, 0.f, 0.f};

  for (int tap = 0; tap < NTAP; ++tap) {
    int du, dv;
    if (rp == 0 && rq == 0)      { du = tap & 1; dv = tap >> 1; }
    else if (rp == 0)            { du = tap;     dv = 0; }
    else if (rq == 0)            { du = 0;       dv = tap; }
    else                         { du = 0;       dv = 0; }
    u32 tapadj = (u32)((du * 66 + dv) * 512);
    const u16* hp = Hy + (size_t)(PB + tap) * 131072;

#pragma unroll 1
    for (int kc = 0; kc < 8; ++kc) {
      u32 ko = (u32)(kc * 64);
      __syncthreads();
#pragma unroll
      for (int i = 0; i < 4; ++i)
        gl_lds16(xp + (gA[i] - tapadj + ko), su + i * 2048 + wave * 512);
#pragma unroll
      for (int i = 0; i < 4; ++i)
        gl_lds16(hp + (gB[i] + ko), su + 8192 + i * 2048 + wave * 512);
      __syncthreads();

#pragma unroll
      for (int ksub = 0; ksub < 2; ++ksub) {
        bf16x8 af[4], bf[4];
#pragma unroll
        for (int ti = 0; ti < 4; ++ti) {
          int row = wm0 + ti * 16 + la;
          int ch = (ksub * 4 + grp) ^ (row & 7);
          af[ti] = *(const bf16x8*)(su + row * 64 + ch * 8);
        }
#pragma unroll
        for (int tj = 0; tj < 4; ++tj) {
          int row = wn0 + tj * 16 + la;
          int ch = (ksub * 4 + grp) ^ (row & 7);
          bf[tj] = *(const bf16x8*)(su + 8192 + row * 64 + ch * 8);
        }
#pragma unroll
        for (int ti = 0; ti < 4; ++ti)
#pragma unroll
          for (int tj = 0; tj < 4; ++tj)
            acc[ti][tj] = __builtin_amdgcn_mfma_f32_16x16x32_bf16(
                af[ti], bf[tj], acc[ti][tj], 0, 0, 0);
      }
    }
  }

  // ---- epilogue: acc -> LDS [o 0..127][m 0..127] (stride 136), dense bf16x8 stores
  __syncthreads();
#pragma unroll
  for (int tj = 0; tj < 4; ++tj) {
    int orow = wn0 + tj * 16 + la;
#pragma unroll
    for (int ti = 0; ti < 4; ++ti)
#pragma unroll
      for (int jp = 0; jp < 2; ++jp) {
        int ml = wm0 + ti * 16 + grp * 4 + jp * 2;
        u32 pk = (u32)f2bf(acc[ti][tj][jp * 2]) |
                 ((u32)f2bf(acc[ti][tj][jp * 2 + 1]) << 16);
        *(u32*)(su + orow * 136 + ml) = pk;
      }
  }
  __syncthreads();
  {
    u16* ybp = yb + 8;
    int o = t >> 1, s = t & 1;
    size_t gb = (size_t)(img * 256 + o0 + o) * CS + PO + m0 + s * 64;
#pragma unroll
    for (int i = 0; i < 8; ++i) {
      int mo = s * 64 + i * 8;
      if (m0 + mo < STLIM)
        *(bf16x8*)(ybp + gb + i * 8) = *(const bf16x8*)(su + o * 136 + mo);
    }
  }
}

// ---------------- pass 2: depthwise FIR on planar y; thread = 4p x 8q z block ----------------
// Derivation (R4 bug fixed): z[p][q] = (1/16) sum f1[s]f1[t] y[p+s-1][q+t-1], f1={1,3,3,1}.
// y-phase row 2a+rp: s = 2a+rp-p+1. With a0 = 2*phb-1, hcol index la -> a = a0+la:
//   rp=0: ip0: 3h[1]+h[2] | ip1: h[1]+3h[2] | ip2: 3h[2]+h[3] | ip3: h[2]+3h[3]
//   rp=1: ip0: h[0]+3h[1] | ip1: 3h[1]+h[2] | ip2: h[1]+3h[2] | ip3: 3h[2]+h[3]
// cols with b0 = 4*qh-1, v index lb -> b = b0+lb, e = jq>>1:
//   rq=0: jq=2e: 3v[e+1]+v[e+2] | jq=2e+1: v[e+1]+3v[e+2]
//   rq=1: jq=2e: v[e]+3v[e+1]   | jq=2e+1: 3v[e+1]+v[e+2]
__global__ void fir2(const u16* __restrict__ yb, float* __restrict__ z) {
  int flat = blockIdx.x * 256 + threadIdx.x;
  int qh = flat & 15, phb = (flat >> 4) & 31, o = (flat >> 9) & 255, n = flat >> 17;
  const u16* cb = yb + 8 + (size_t)(n * 256 + o) * CS;
  int a0 = 2 * phb - 1;
  int b0 = 4 * qh - 1;

  float out[4][8];
#pragma unroll
  for (int i = 0; i < 4; ++i)
#pragma unroll
    for (int j = 0; j < 8; ++j) out[i][j] = 0.f;

  const int PO_[4] = {0, 4296, 8456, 12680};
  const int WP_[4] = {66, 64, 66, 64};
  const int HA_[4] = {65, 65, 64, 64};
  const int WB_[4] = {65, 64, 65, 64};

#pragma unroll
  for (int ph = 0; ph < 4; ++ph) {
    int rp = ph >> 1, rq = ph & 1;
    const u16* pb = cb + PO_[ph];
    float hcol[4][8];
#pragma unroll
    for (int la = 0; la < 4; ++la) {
      if (rp == 0 && la == 0) continue;          // row unused for rp=0 (folds at compile time)
      int ag = a0 + la;
      bool rv = (ag >= 0) && (ag < HA_[ph]);
      const u16* rb = pb + (ag * WP_[ph] + b0 - 1);   // even offset; pads keep it in d_ws
      u32 ls[4];
      ls[0] = *(const u32*)(rb);
      ls[1] = *(const u32*)(rb + 2);
      ls[2] = *(const u32*)(rb + 4);
      ls[3] = *(const u32*)(rb + 6);
      float v[6];
#pragma unroll
      for (int lb = 0; lb < 6; ++lb) {
        int jj = lb + 1;                          // rb[jj] = col b0-1+jj = b0+lb
        u32 w16 = (jj & 1) ? (ls[jj >> 1] >> 16) : (ls[jj >> 1] & 0xffffu);
        float fv = __uint_as_float(w16 << 16);
        int bg = b0 + lb;
        bool ok = rv && (bg >= 0) && (bg < WB_[ph]);
        v[lb] = ok ? fv : 0.f;
      }
#pragma unroll
      for (int e = 0; e < 4; ++e) {
        if (rq == 0) {
          hcol[la][2 * e]     = 3.f * v[e + 1] + v[e + 2];
          hcol[la][2 * e + 1] = v[e + 1] + 3.f * v[e + 2];
        } else {
          hcol[la][2 * e]     = v[e] + 3.f * v[e + 1];
          hcol[la][2 * e + 1] = 3.f * v[e + 1] + v[e + 2];
        }
      }
    }
#pragma unroll
    for (int jq = 0; jq < 8; ++jq) {
      if (rp == 0) {
        out[0][jq] += 3.f * hcol[1][jq] + hcol[2][jq];
        out[1][jq] += hcol[1][jq] + 3.f * hcol[2][jq];
        out[2][jq] += 3.f * hcol[2][jq] + hcol[3][jq];
        out[3][jq] += hcol[2][jq] + 3.f * hcol[3][jq];
      } else {
        out[0][jq] += hcol[0][jq] + 3.f * hcol[1][jq];
        out[1][jq] += 3.f * hcol[1][jq] + hcol[2][jq];
        out[2][jq] += hcol[1][jq] + 3.f * hcol[2][jq];
        out[3][jq] += 3.f * hcol[2][jq] + hcol[3][jq];
      }
    }
  }

  float* zb = z + ((size_t)(n * 256 + o) * 128 + phb * 4) * 128 + qh * 8;
#pragma unroll
  for (int ip = 0; ip < 4; ++ip) {
    f32x4 v0, v1;
#pragma unroll
    for (int j = 0; j < 4; ++j) { v0[j] = out[ip][j] * 0.0625f; v1[j] = out[ip][j + 4] * 0.0625f; }
    *(f32x4*)(zb + (size_t)ip * 128) = v0;
    *(f32x4*)(zb + (size_t)ip * 128 + 4) = v1;
  }
}

// ================= fallback path (R2, proven): FIR-folded fused conv =================
__global__ void wprep36(const float* __restrict__ w, u16* __restrict__ Hm) {
  __shared__ float wl[4608];
  __shared__ float red[256];
  int o = blockIdx.x, t = threadIdx.x;
  const float* wo = w + (size_t)o * 4608;
  float s = 0.f;
  for (int j = t; j < 4608; j += 256) { float v = wo[j]; wl[j] = v; s += v * v; }
  red[t] = s;
  __syncthreads();
  for (int st = 128; st; st >>= 1) { if (t < st) red[t] += red[t + st]; __syncthreads(); }
  float demod = rsqrtf(red[0] * (1.0f / 4608.0f) + 1e-6f);
  float scale = demod * 0.014731391274719739f;
  const float F1[4] = {1.f, 3.f, 3.f, 1.f};
  for (int i = t; i < 512; i += 256) {
    float wm[9];
    for (int k = 0; k < 9; ++k) wm[k] = wl[i * 9 + k] * scale;
    for (int rp = 0; rp < 2; ++rp)
      for (int rq = 0; rq < 2; ++rq)
        for (int u = 0; u < 3; ++u)
          for (int v = 0; v < 3; ++v) {
            int s_ = 2 - 2 * u + rp, t_ = 2 - 2 * v + rq;
            float g = 0.f;
            for (int dy = 0; dy < 3; ++dy) {
              int a = dy + 1 - s_;
              if (a < 0 || a > 3) continue;
              for (int dx = 0; dx < 3; ++dx) {
                int b = dx + 1 - t_;
                if (b < 0 || b > 3) continue;
                g += wm[dy * 3 + dx] * (F1[a] * F1[b]);
              }
            }
            g *= 0.0625f;
            Hm[(size_t)((rp * 2 + rq) * 9 + u * 3 + v) * 131072 + (size_t)o * 512 + i] = f2bf(g);
          }
  }
}

__global__ __launch_bounds__(256) void conv_main(const u16* __restrict__ xp,
                                                 const u16* __restrict__ Hm,
                                                 float* __restrict__ z) {
  __shared__ __align__(16) float smemf[8448];
  u16* su = (u16*)smemf;
  int bid = blockIdx.x;
  int sub = bid & 7;
  int rp = sub >> 2;
  int o0 = (sub & 3) * 64;
  int mtile = bid >> 3;
  int n_img = mtile >> 5;
  int hp0 = (mtile & 31) * 2;
  int t = threadIdx.x;
  int wave = t >> 6, lane = t & 63;
  int wm0 = (wave & 1) * 64;
  int wn0 = (wave >> 1) * 32;
  int la = lane & 15;
  int ks = (lane >> 4) * 8;
  int rsel = t >> 2;
  int koff = (t & 3) * 8;
  f32x4 acc[2][4][2];
#pragma unroll
  for (int a = 0; a < 2; ++a)
#pragma unroll
    for (int b = 0; b < 4; ++b)
#pragma unroll
      for (int c = 0; c < 2; ++c)
        acc[a][b][c] = (f32x4){0.f, 0.f, 0.f, 0.f};
#pragma unroll 1
  for (int tap = 0; tap < 9; ++tap) {
    int du = tap / 3, dv = tap - du * 3;
    const u16* gA0 = xp + ((size_t)(n_img * 66 + hp0 + du) * 66 + dv) * 512;
    const u16* gB0 = Hm + (size_t)(rp * 18 + tap) * 131072 + (size_t)(o0 + rsel) * 512 + koff;
    const u16* gAr0 = gA0 + (size_t)rsel * 512 + koff;
    const u16* gAr1 = gA0 + (size_t)(66 + rsel) * 512 + koff;
#pragma unroll 1
    for (int kc = 0; kc < 16; ++kc) {
      int c0 = kc * 32;
      __syncthreads();
      gl_lds16(gAr0 + c0, su + wave * 512);
      gl_lds16(gAr1 + c0, su + 2048 + wave * 512);
      gl_lds16(gB0 + c0,              su + 4096 + wave * 512);
      gl_lds16(gB0 + 9 * 131072 + c0, su + 6144 + wave * 512);
      __syncthreads();
      bf16x8 af[4];
#pragma unroll
      for (int ti = 0; ti < 4; ++ti)
        af[ti] = *(const bf16x8*)(su + (wm0 + ti * 16 + la) * 32 + ks);
      bf16x8 bfr[2][2];
#pragma unroll
      for (int rqq = 0; rqq < 2; ++rqq)
#pragma unroll
        for (int tj = 0; tj < 2; ++tj)
          bfr[rqq][tj] = *(const bf16x8*)(su + 4096 + rqq * 2048 + (wn0 + tj * 16 + la) * 32 + ks);
#pragma unroll
      for (int rqq = 0; rqq < 2; ++rqq)
#pragma unroll
        for (int ti = 0; ti < 4; ++ti)
#pragma unroll
          for (int tj = 0; tj < 2; ++tj)
            acc[rqq][ti][tj] = __builtin_amdgcn_mfma_f32_16x16x32_bf16(
                af[ti], bfr[rqq][tj], acc[rqq][ti][tj], 0, 0, 0);
    }
  }
  __syncthreads();
  float* lws = smemf + wave * 2112;
  int p = 2 * (hp0 + (wave & 1)) + rp;
#pragma unroll
  for (int tj = 0; tj < 2; ++tj) {
#pragma unroll
    for (int rqq = 0; rqq < 2; ++rqq)
#pragma unroll
      for (int ti = 0; ti < 4; ++ti) {
        int wqb = ti * 16 + (lane >> 4) * 4;
        f32x4 v = acc[rqq][ti][tj];
#pragma unroll
        for (int r = 0; r < 4; ++r)
          lws[la * 132 + 2 * (wqb + r) + rqq] = v[r];
      }
    __syncthreads();
    int obase = o0 + wn0 + tj * 16;
#pragma unroll
    for (int c = 0; c < 8; ++c) {
      int idx = c * 64 + lane;
      int ol = idx >> 5, q4 = (idx & 31) * 4;
      f32x4 vv = *(const f32x4*)(lws + ol * 132 + q4);
      *(f32x4*)(z + (((size_t)n_img * 256 + obase + ol) * 128 + p) * 128 + q4) = vv;
    }
    __syncthreads();
  }
}

extern "C" void kernel_launch(void* const* d_in, const int* in_sizes, int n_in,
                              void* d_out, int out_size, void* d_ws, size_t ws_size,
                              hipStream_t stream) {
  const float* x = (const float*)d_in[0];
  const float* w = (const float*)d_in[1];
  float* z = (float*)d_out;
  u16* xp = (u16*)d_ws;

  if (ws_size >= WS_NEED) {
    u16* yb = (u16*)((char*)d_ws + XP_BYTES);
    u16* hy = (u16*)((char*)d_ws + HY_OFF);
    xprep<<<4096, 256, 0, stream>>>(x, xp);       // self-zeroing xp halos; no memset needed
    wprep9<<<256, 256, 0, stream>>>(w, hy);
    conv_y<<<2112, 256, 0, stream>>>(xp, hy, yb);
    fir2<<<4096, 256, 0, stream>>>(yb, z);
  } else {
    u16* Hm = (u16*)((char*)d_ws + XP_BYTES);
    hipMemsetAsync(xp, 0, XP_BYTES, stream);
    xprep<<<4096, 256, 0, stream>>>(x, xp);
    wprep36<<<256, 256, 0, stream>>>(w, Hm);
    conv_main<<<2048, 256, 0, stream>>>(xp, Hm, z);
  }
}